// Round 1
// baseline (128.625 us; speedup 1.0000x reference)
//
#include <hip/hip_runtime.h>
#include <math.h>

// Problem constants (match reference config)
#define GPB    8      // k-vectors per reciprocal block
#define GTOT   729    // (2*NMAX+1)^3, NMAX=4
#define GMAX   46     // ceil(364/8): worst-case active half-sphere k's / GPB
#define KMAX   (GMAX*GPB)   // 368 compacted k slots per system (padded)
#define APB    16     // atoms per real-space block (256 thr = 4 waves x 4 atoms)
#define STRIDE 344    // partial slots per system (covers legacy 250+92 too)

__device__ __forceinline__ float wave_reduce(float v) {
    #pragma unroll
    for (int off = 32; off > 0; off >>= 1) v += __shfl_down(v, off, 64);
    return v;
}

// Abramowitz & Stegun 7.1.26: erfc(x) for x>=0, |abs err| <= 1.5e-7.
// 1 rcp + 1 exp + 5 fma + 2 mul vs ~30-40 instr libm erfcf.
__device__ __forceinline__ float fast_erfc(float x) {
    float t = __builtin_amdgcn_rcpf(fmaf(0.3275911f, x, 1.0f));
    float p = fmaf(1.061405429f, t, -1.453152027f);
    p = fmaf(p, t, 1.421413741f);
    p = fmaf(p, t, -0.284496736f);
    p = fmaf(p, t, 0.254829592f);
    return p * t * __expf(-x * x);
}

// -------- prologue: pack positions+charge into float4 for 1-line gathers ----
__global__ __launch_bounds__(256)
void pack_pq(const float* __restrict__ pos, const float* __restrict__ chg,
             float4* __restrict__ pq, int T)
{
    int t = blockIdx.x * 256 + threadIdx.x;
    if (t < T)
        pq[t] = make_float4(pos[3*t], pos[3*t+1], pos[3*t+2], chg[t]);
}

// -------- prologue: compact active k-vectors per system (deterministic) ----
__global__ __launch_bounds__(64)
void build_kvecs(const float* __restrict__ cell, float4* __restrict__ kcomp,
                 int* __restrict__ kcnt)
{
    const float TWO_PI = 6.283185307179586f;
    const float INV4A2 = 2.7777777777f;           // 1/(4*ALPHA^2)
    const float KC2    = 1.0f;

    int b    = blockIdx.x;
    int lane = threadIdx.x;                       // 0..63, one wave

    const float* C = cell + 9 * b;
    float m00=C[0], m01=C[1], m02=C[2];
    float m10=C[3], m11=C[4], m12=C[5];
    float m20=C[6], m21=C[7], m22=C[8];
    float a00 = m11*m22 - m12*m21;
    float a01 = m02*m21 - m01*m22;
    float a02 = m01*m12 - m02*m11;
    float a10 = m12*m20 - m10*m22;
    float a11 = m00*m22 - m02*m20;
    float a12 = m02*m10 - m00*m12;
    float a20 = m10*m21 - m11*m20;
    float a21 = m01*m20 - m00*m21;
    float a22 = m00*m11 - m01*m10;
    float det = m00*a00 + m01*a10 + m02*a20;
    float invdet = 1.0f / det;
    float vol = fabsf(det);

    int cnt = 0;
    for (int base = 0; base < GTOT; base += 64) {
        int g = base + lane;
        float kx = 0.f, ky = 0.f, kz = 0.f, cf = 0.f;
        if (g < GTOT) {
            int ix = g / 81, rem = g - ix * 81;
            int iy = rem / 9, iz = rem - iy * 9;
            int nx = ix - 4, ny = iy - 4, nz = iz - 4;
            bool pos_half = (nx > 0) || (nx == 0 && (ny > 0 || (ny == 0 && nz > 0)));
            if (pos_half) {
                float fx = (float)nx, fy = (float)ny, fz = (float)nz;
                kx = TWO_PI * invdet * (fx*a00 + fy*a01 + fz*a02);
                ky = TWO_PI * invdet * (fx*a10 + fy*a11 + fz*a12);
                kz = TWO_PI * invdet * (fx*a20 + fy*a21 + fz*a22);
                float k2 = kx*kx + ky*ky + kz*kz;
                if (k2 > 1e-10f && k2 <= KC2) {
                    // 2 * [4*pi*exp(-k2/4a^2)/k2] / (2*vol)  (half-sphere doubling)
                    cf = 12.566370614359172f * __expf(-k2 * INV4A2) / (k2 * vol);
                }
            }
        }
        bool act = (cf != 0.f);
        unsigned long long m = __ballot(act);
        if (act) {
            int off = __popcll(m & ((1ull << lane) - 1ull));
            kcomp[b * KMAX + cnt + off] = make_float4(kx, ky, kz, cf);
        }
        cnt += (int)__popcll(m);
    }
    // pad to a multiple of GPB with dead entries so groups unroll densely
    int padded = ((cnt + GPB - 1) / GPB) * GPB;
    if (lane < padded - cnt)
        kcomp[b * KMAX + cnt + lane] = make_float4(0.f, 0.f, 0.f, 0.f);
    if (lane == 0) kcnt[b] = padded / GPB;        // active group count
}

// -------- fused main kernel (compacted recip + packed real) ----------------
__global__ __launch_bounds__(256)
void ewald_fused2(const float4* __restrict__ pq,    // packed [T]
                  const float*  __restrict__ cell,  // [Bn,3,3]
                  const int*    __restrict__ nm,    // [T,K]
                  const int*    __restrict__ shifts,// [T,K,3]
                  const int*    __restrict__ nnb,   // [T]
                  const float4* __restrict__ kcomp, // [Bn,KMAX]
                  const int*    __restrict__ kcnt,  // [Bn]
                  float* __restrict__ partial,      // [Bn][STRIDE]
                  int T, int N, int K, int Bn, int CB)
{
    __shared__ float4 skv[GPB];
    __shared__ float  redA[4][GPB];
    __shared__ float  redB[4][GPB];
    __shared__ float  redr[4];

    const float ALPHA       = 0.3f;
    const float INV_SQRT_PI = 0.5641895835477563f;

    int blk  = blockIdx.x;
    int lane = threadIdx.x & 63;
    int w    = threadIdx.x >> 6;

    if (blk < CB) {
        // ======================= reciprocal space ==========================
        int b    = blk / GMAX;
        int grp  = blk - b * GMAX;
        int slot = b * STRIDE + (N / APB) + grp;
        int ng   = kcnt[b];
        if (grp >= ng) {                           // dead block: no atom loop
            if (threadIdx.x == 0) partial[slot] = 0.f;
            return;
        }

        if (threadIdx.x < GPB)
            skv[threadIdx.x] = kcomp[b * KMAX + grp * GPB + threadIdx.x];
        __syncthreads();

        float kvx[GPB], kvy[GPB], kvz[GPB];
        #pragma unroll
        for (int gi = 0; gi < GPB; ++gi) {
            float4 v = skv[gi];
            kvx[gi] = v.x; kvy[gi] = v.y; kvz[gi] = v.z;
        }

        float Sre[GPB], Sim[GPB];
        #pragma unroll
        for (int gi = 0; gi < GPB; ++gi) { Sre[gi] = 0.f; Sim[gi] = 0.f; }

        // dense inner loop, 2 atoms per iteration (amortize k-regs + loop cost)
        const float4* pb = pq + (size_t)b * N;
        int a = threadIdx.x;
        for (; a + 256 < N; a += 512) {
            float4 v0 = pb[a];
            float4 v1 = pb[a + 256];
            #pragma unroll
            for (int gi = 0; gi < GPB; ++gi) {
                float ph0 = fmaf(v0.x, kvx[gi], fmaf(v0.y, kvy[gi], v0.z * kvz[gi]));
                float ph1 = fmaf(v1.x, kvx[gi], fmaf(v1.y, kvy[gi], v1.z * kvz[gi]));
                float s0, c0, s1, c1;
                __sincosf(ph0, &s0, &c0);
                __sincosf(ph1, &s1, &c1);
                Sre[gi] = fmaf(v0.w, c0, Sre[gi]);
                Sim[gi] = fmaf(v0.w, s0, Sim[gi]);
                Sre[gi] = fmaf(v1.w, c1, Sre[gi]);
                Sim[gi] = fmaf(v1.w, s1, Sim[gi]);
            }
        }
        if (a < N) {                               // tail atom
            float4 v0 = pb[a];
            #pragma unroll
            for (int gi = 0; gi < GPB; ++gi) {
                float ph0 = fmaf(v0.x, kvx[gi], fmaf(v0.y, kvy[gi], v0.z * kvz[gi]));
                float s0, c0;
                __sincosf(ph0, &s0, &c0);
                Sre[gi] = fmaf(v0.w, c0, Sre[gi]);
                Sim[gi] = fmaf(v0.w, s0, Sim[gi]);
            }
        }

        // single-sync reduction: wave partials -> LDS -> wave 0 finishes
        #pragma unroll
        for (int gi = 0; gi < GPB; ++gi) {
            float sr = wave_reduce(Sre[gi]);
            float si = wave_reduce(Sim[gi]);
            if (lane == 0) { redA[w][gi] = sr; redB[w][gi] = si; }
        }
        __syncthreads();
        if (threadIdx.x < 64) {
            float e = 0.f;
            if (threadIdx.x < GPB) {
                int gi = threadIdx.x;
                float SR = redA[0][gi] + redA[1][gi] + redA[2][gi] + redA[3][gi];
                float SI = redB[0][gi] + redB[1][gi] + redB[2][gi] + redB[3][gi];
                e = skv[gi].w * (SR * SR + SI * SI);
            }
            e = wave_reduce(e);
            if (threadIdx.x == 0) partial[slot] = e;
        }
    } else {
        // ========================== real space =============================
        int rb = blk - CB;
        int t0 = rb * APB;
        int sys = t0 / N;                 // APB divides N -> block in one system

        float val = 0.0f;
        #pragma unroll
        for (int i = 0; i < APB/4; ++i) {
            int t = t0 + w * (APB/4) + i;
            float4 vi = pq[t];
            float xi = vi.x, yi = vi.y, zi = vi.z, qi = vi.w;
            if (lane == 0) val -= ALPHA * INV_SQRT_PI * qi * qi; // self term
            int nn = nnb[t];
            for (int k = lane; k < K; k += 64) {
                int p = t * K + k;
                int j = nm[p];
                bool msk = (j >= 0) && (k < nn);
                if (msk) {
                    int sx = shifts[3*p], sy = shifts[3*p+1], sz = shifts[3*p+2];
                    float ox = 0.f, oy = 0.f, oz = 0.f;
                    if ((sx | sy | sz) != 0) {
                        const float* C = cell + 9 * sys;
                        float fx = (float)sx, fy = (float)sy, fz = (float)sz;
                        ox = fx*C[0] + fy*C[3] + fz*C[6];
                        oy = fx*C[1] + fy*C[4] + fz*C[7];
                        oz = fx*C[2] + fy*C[5] + fz*C[8];
                    }
                    float4 vj = pq[j];
                    float dx = vj.x + ox - xi;
                    float dy = vj.y + oy - yi;
                    float dz = vj.z + oz - zi;
                    float r2 = fmaf(dx, dx, fmaf(dy, dy, dz*dz));
                    float rinv = rsqrtf(r2);
                    float d = r2 * rinv;
                    val += 0.5f * qi * vj.w * fast_erfc(ALPHA * d) * rinv;
                }
            }
        }

        val = wave_reduce(val);
        if (lane == 0) redr[w] = val;
        __syncthreads();
        if (threadIdx.x == 0) {
            int rb_in_sys = rb - sys * (N / APB);
            partial[sys * STRIDE + rb_in_sys] =
                redr[0] + redr[1] + redr[2] + redr[3];
        }
    }
}

// -------- legacy fallback (workspace too small): original fused kernel -----
template <bool PACKED>
__global__ __launch_bounds__(256)
void ewald_fused(const float4* __restrict__ pq,
                 const float*  __restrict__ pos,
                 const float*  __restrict__ chg,
                 const float*  __restrict__ cell,
                 const int*    __restrict__ nm,
                 const int*    __restrict__ shifts,
                 const int*    __restrict__ nnb,
                 float* __restrict__ partial,
                 int T, int N, int K, int Bn, int CB)
{
    __shared__ float red[16];

    const float TWO_PI  = 6.283185307179586f;
    const float ALPHA   = 0.3f;
    const float INV4A2  = 2.7777777777f;
    const float KC2     = 1.0f;
    const float INV_SQRT_PI = 0.5641895835477563f;

    int blk = blockIdx.x;

    if (blk < CB) {
        int gpb_groups = (GTOT + GPB - 1) / GPB;
        int b   = blk / gpb_groups;
        int grp = blk % gpb_groups;

        const float* C = cell + 9 * b;
        float m00=C[0], m01=C[1], m02=C[2];
        float m10=C[3], m11=C[4], m12=C[5];
        float m20=C[6], m21=C[7], m22=C[8];
        float a00 = m11*m22 - m12*m21;
        float a01 = m02*m21 - m01*m22;
        float a02 = m01*m12 - m02*m11;
        float a10 = m12*m20 - m10*m22;
        float a11 = m00*m22 - m02*m20;
        float a12 = m02*m10 - m00*m12;
        float a20 = m10*m21 - m11*m20;
        float a21 = m01*m20 - m00*m21;
        float a22 = m00*m11 - m01*m10;
        float det = m00*a00 + m01*a10 + m02*a20;
        float invdet = 1.0f / det;
        float vol = fabsf(det);

        float kvx[GPB], kvy[GPB], kvz[GPB], coef[GPB];
        bool any = false;
        #pragma unroll
        for (int gi = 0; gi < GPB; ++gi) {
            int g = grp * GPB + gi;
            float cf = 0.f, kx = 0.f, ky = 0.f, kz = 0.f;
            if (g < GTOT) {
                int ix = g / 81, rem = g - ix * 81;
                int iy = rem / 9, iz = rem - iy * 9;
                int nx = ix - 4, ny = iy - 4, nz = iz - 4;
                bool pos_half = (nx > 0) || (nx == 0 && (ny > 0 || (ny == 0 && nz > 0)));
                if (pos_half) {
                    float fx = (float)nx, fy = (float)ny, fz = (float)nz;
                    kx = TWO_PI * invdet * (fx*a00 + fy*a01 + fz*a02);
                    ky = TWO_PI * invdet * (fx*a10 + fy*a11 + fz*a12);
                    kz = TWO_PI * invdet * (fx*a20 + fy*a21 + fz*a22);
                    float k2 = kx*kx + ky*ky + kz*kz;
                    if (k2 > 1e-10f && k2 <= KC2) {
                        cf = 12.566370614359172f * __expf(-k2 * INV4A2) / (k2 * vol);
                    }
                }
            }
            kvx[gi] = kx; kvy[gi] = ky; kvz[gi] = kz; coef[gi] = cf;
            any = any || (cf != 0.f);
        }

        int slot = b * STRIDE + (N / APB) + grp;
        if (!any) {
            if (threadIdx.x == 0) partial[slot] = 0.f;
            return;
        }

        float Sre[GPB], Sim[GPB];
        #pragma unroll
        for (int gi = 0; gi < GPB; ++gi) { Sre[gi] = 0.f; Sim[gi] = 0.f; }

        for (int a = threadIdx.x; a < N; a += 256) {
            float x, y, z, qa;
            if (PACKED) {
                float4 v = pq[(size_t)b * N + a];
                x = v.x; y = v.y; z = v.z; qa = v.w;
            } else {
                const float* pb = pos + (size_t)3 * (b * N + a);
                x = pb[0]; y = pb[1]; z = pb[2];
                qa = chg[(size_t)b * N + a];
            }
            #pragma unroll
            for (int gi = 0; gi < GPB; ++gi) {
                if (coef[gi] != 0.f) {
                    float ph = x*kvx[gi] + y*kvy[gi] + z*kvz[gi];
                    float s, c;
                    __sincosf(ph, &s, &c);
                    Sre[gi] = fmaf(qa, c, Sre[gi]);
                    Sim[gi] = fmaf(qa, s, Sim[gi]);
                }
            }
        }

        int lane = threadIdx.x & 63;
        int w    = threadIdx.x >> 6;
        float e_acc = 0.f;
        #pragma unroll
        for (int gi = 0; gi < GPB; ++gi) {
            if (coef[gi] != 0.f) {
                float sr = wave_reduce(Sre[gi]);
                float si = wave_reduce(Sim[gi]);
                if (lane == 0) { red[2*w] = sr; red[2*w+1] = si; }
                __syncthreads();
                if (threadIdx.x == 0) {
                    float SR = red[0] + red[2] + red[4] + red[6];
                    float SI = red[1] + red[3] + red[5] + red[7];
                    e_acc += coef[gi] * (SR*SR + SI*SI);
                }
                __syncthreads();
            }
        }
        if (threadIdx.x == 0) partial[slot] = e_acc;
    } else {
        int rb = blk - CB;
        int t0 = rb * APB;
        int sys = t0 / N;
        int lane = threadIdx.x & 63;
        int w    = threadIdx.x >> 6;

        float val = 0.0f;
        #pragma unroll
        for (int i = 0; i < APB/4; ++i) {
            int t = t0 + w * (APB/4) + i;
            float xi, yi, zi, qi;
            if (PACKED) {
                float4 v = pq[t];
                xi = v.x; yi = v.y; zi = v.z; qi = v.w;
            } else {
                xi = pos[3*t]; yi = pos[3*t+1]; zi = pos[3*t+2];
                qi = chg[t];
            }
            if (lane == 0) val -= ALPHA * INV_SQRT_PI * qi * qi;
            int nn = nnb[t];
            for (int k = lane; k < K; k += 64) {
                int p = t * K + k;
                int j = nm[p];
                bool msk = (j >= 0) && (k < nn);
                if (msk) {
                    int sx = shifts[3*p], sy = shifts[3*p+1], sz = shifts[3*p+2];
                    float ox = 0.f, oy = 0.f, oz = 0.f;
                    if ((sx | sy | sz) != 0) {
                        const float* C = cell + 9 * sys;
                        float fx = (float)sx, fy = (float)sy, fz = (float)sz;
                        ox = fx*C[0] + fy*C[3] + fz*C[6];
                        oy = fx*C[1] + fy*C[4] + fz*C[7];
                        oz = fx*C[2] + fy*C[5] + fz*C[8];
                    }
                    float xj, yj, zj, qj;
                    if (PACKED) {
                        float4 v = pq[j];
                        xj = v.x; yj = v.y; zj = v.z; qj = v.w;
                    } else {
                        xj = pos[3*j]; yj = pos[3*j+1]; zj = pos[3*j+2];
                        qj = chg[j];
                    }
                    float dx = xj + ox - xi;
                    float dy = yj + oy - yi;
                    float dz = zj + oz - zi;
                    float r2 = fmaf(dx, dx, fmaf(dy, dy, dz*dz));
                    float rinv = rsqrtf(r2);
                    float d = r2 * rinv;
                    val += 0.5f * qi * qj * erfcf(ALPHA * d) * rinv;
                }
            }
        }

        val = wave_reduce(val);
        if (lane == 0) red[w] = val;
        __syncthreads();
        if (threadIdx.x == 0) {
            int rb_in_sys = rb - sys * (N / APB);
            partial[sys * STRIDE + rb_in_sys] =
                red[0] + red[1] + red[2] + red[3];
        }
    }
}

// -------- epilogue: per-system sum of partials, apply Coulomb constant -----
__global__ __launch_bounds__(256)
void final_reduce(const float* __restrict__ partial, float* __restrict__ out,
                  int nslots)
{
    __shared__ float red[4];
    const float COUL = 14.399645351950548f;
    int b = blockIdx.x;
    float v = 0.f;
    for (int s = threadIdx.x; s < nslots; s += 256)
        v += partial[b * STRIDE + s];
    v = wave_reduce(v);
    int lane = threadIdx.x & 63, w = threadIdx.x >> 6;
    if (lane == 0) red[w] = v;
    __syncthreads();
    if (threadIdx.x == 0)
        out[b] = COUL * (red[0] + red[1] + red[2] + red[3]);
}

extern "C" void kernel_launch(void* const* d_in, const int* in_sizes, int n_in,
                              void* d_out, int out_size, void* d_ws, size_t ws_size,
                              hipStream_t stream) {
    const float* pos    = (const float*)d_in[0];
    const float* chg    = (const float*)d_in[1];
    const float* cellp  = (const float*)d_in[2];
    const int*   nm     = (const int*)d_in[3];
    const int*   shifts = (const int*)d_in[4];
    const int*   nnb    = (const int*)d_in[5];

    int T  = in_sizes[1];          // 64000
    int Bn = in_sizes[2] / 9;      // 16
    int N  = T / Bn;               // 4000
    int K  = in_sizes[3] / T;      // 64
    int RB = T / APB;              // 4000 real blocks

    // workspace layout: partial | pq (float4) | kcomp (float4) | kcnt (int)
    size_t partBytes = (size_t)Bn * STRIDE * sizeof(float);
    size_t packOff   = ((partBytes + 255) / 256) * 256;
    size_t packBytes = (size_t)T * sizeof(float4);
    size_t kOff      = ((packOff + packBytes + 255) / 256) * 256;
    size_t kBytes    = (size_t)Bn * KMAX * sizeof(float4);
    size_t cntOff    = kOff + kBytes;
    size_t cntBytes  = (size_t)Bn * sizeof(int);

    float* partial = (float*)d_ws;

    if (ws_size >= cntOff + cntBytes) {
        // ---- compacted path ----
        float4* pq    = (float4*)((char*)d_ws + packOff);
        float4* kcomp = (float4*)((char*)d_ws + kOff);
        int*    kcnt  = (int*)((char*)d_ws + cntOff);
        int CB = Bn * GMAX;                         // 736 recip blocks (many early-exit)
        pack_pq<<<(T + 255) / 256, 256, 0, stream>>>(pos, chg, pq, T);
        build_kvecs<<<Bn, 64, 0, stream>>>(cellp, kcomp, kcnt);
        ewald_fused2<<<CB + RB, 256, 0, stream>>>(
            pq, cellp, nm, shifts, nnb, kcomp, kcnt, partial, T, N, K, Bn, CB);
        final_reduce<<<Bn, 256, 0, stream>>>(partial, (float*)d_out, N/APB + GMAX);
    } else {
        // ---- legacy fallback ----
        int CB = Bn * ((GTOT + GPB - 1) / GPB);
        int nslots = (N / APB) + ((GTOT + GPB - 1) / GPB);
        bool packed = (ws_size >= packOff + packBytes);
        if (packed) {
            float4* pq = (float4*)((char*)d_ws + packOff);
            pack_pq<<<(T + 255) / 256, 256, 0, stream>>>(pos, chg, pq, T);
            ewald_fused<true><<<CB + RB, 256, 0, stream>>>(
                pq, pos, chg, cellp, nm, shifts, nnb, partial, T, N, K, Bn, CB);
        } else {
            ewald_fused<false><<<CB + RB, 256, 0, stream>>>(
                nullptr, pos, chg, cellp, nm, shifts, nnb, partial, T, N, K, Bn, CB);
        }
        final_reduce<<<Bn, 256, 0, stream>>>(partial, (float*)d_out, nslots);
    }
}